// Round 4
// baseline (760.439 us; speedup 1.0000x reference)
//
#include <hip/hip_runtime.h>
#include <hip/hip_bf16.h>

// ---------------------------------------------------------------------------
// Attention block: B=2 S=2048 D=4096 H=32 KV=8 HD=128 (GQA N_REP=4, causal)
// Pipeline: cvt -> GEMM8(qkv) -> RoPE/scatter -> flash-attn -> GEMM8(out)
// GEMM: 256x256 tile, BK=64, 8-phase counted-vmcnt schedule (T2+T3+T4+T5).
// ---------------------------------------------------------------------------

typedef __attribute__((ext_vector_type(8))) short  s8v;   // 8 x bf16 (4 VGPR)
typedef __attribute__((ext_vector_type(4))) short  s4v;   // 4 x bf16 (2 VGPR)
typedef __attribute__((ext_vector_type(4))) float  f4v;
typedef __attribute__((ext_vector_type(2))) float  f2v;
typedef __attribute__((ext_vector_type(2))) unsigned int u2v;
typedef __attribute__((ext_vector_type(4))) unsigned int u4v;

typedef __attribute__((address_space(3))) void lds_void;
typedef __attribute__((address_space(1))) void g_void;

#define GLDS16(gp, lp) __builtin_amdgcn_global_load_lds((g_void*)(gp), (lds_void*)(lp), 16, 0, 0)

__device__ __forceinline__ unsigned short f2b(float f) {  // f32 -> bf16 RNE
  unsigned u = __builtin_bit_cast(unsigned, f);
  u += 0x7fffu + ((u >> 16) & 1u);
  return (unsigned short)(u >> 16);
}
__device__ __forceinline__ unsigned pk2(float a, float b) {
  return (unsigned)f2b(a) | ((unsigned)f2b(b) << 16);
}

// inline-asm MFMAs (volatile; s_nop guards at every MFMA->VALU read-back)
__device__ __forceinline__ void mfma32(f4v& d, s8v a, s8v b) {
  asm volatile("v_mfma_f32_16x16x32_bf16 %0, %1, %2, %0" : "+v"(d) : "v"(a), "v"(b));
}
__device__ __forceinline__ void mfma16(f4v& d, s4v a, s4v b) {
  asm volatile("v_mfma_f32_16x16x16_bf16 %0, %1, %2, %0" : "+v"(d) : "v"(a), "v"(b));
}
__device__ __forceinline__ s4v tr_read(const char* p, int imm) {
  s4v r;
  asm volatile("ds_read_b64_tr_b16 %0, %1 offset:%2"
               : "=v"(r) : "v"((lds_void*)p), "n"(imm));
  return r;
}

// ---------------------------------------------------------------------------
// f32 -> bf16 convert
// ---------------------------------------------------------------------------
__global__ __launch_bounds__(256) void cvt_bf16(const float* __restrict__ s,
                                                unsigned short* __restrict__ d, int n4) {
  const int i = blockIdx.x * 256 + threadIdx.x;
  if (i >= n4) return;
  f4v v = *(const f4v*)(s + (size_t)i * 4);
  u2v r;
  r.x = pk2(v[0], v[1]);
  r.y = pk2(v[2], v[3]);
  *(u2v*)(d + (size_t)i * 4) = r;
}

// ---------------------------------------------------------------------------
// 8-phase GEMM, C[M][N] = A[M][K] * B[N][K]^T (bf16 in, f32 out).
// 256x256 tile, BK=64, 512 thr = 8 waves (2M x 4N), 128 KiB LDS double-buffer.
// LDS per buf d (base d*65536): A [256 rows][128B] at +0, B at +32768.
// Swizzle: byte-in-row ^= (row&7)<<4 (2-way-free b128 frag reads), applied by
// pre-swizzling the global source column (linear gload_lds dest, rule #21).
// Schedule per iter (tiles t=2i even->buf0, t+1->buf1):
//   ph0 q(0,0)buf0 rd a0-3,b0-1 stg t+1.B0 | ph1 q(1,0) rd a4-7 stg t+1.B1
//   ph2 q(0,1) rd b2-3 stg t+2.A0          | ph3 q(1,1) stg t+2.A1, vmcnt(4)
//   ph4-7 mirror on buf1, stages t+2.B0,B1,t+3.A0,A1, vmcnt(4) at ph7.
// vmcnt(4) before closing barrier => older stages landed for ALL waves after
// the barrier; per-phase lgkmcnt(0) drains reads before regions get restaged.
// ---------------------------------------------------------------------------
#define BAR      asm volatile("s_barrier" ::: "memory")
#define WLGKM    do { asm volatile("s_waitcnt lgkmcnt(0)" ::: "memory"); \
                      __builtin_amdgcn_sched_barrier(0); } while (0)
#define WVM4     do { asm volatile("s_waitcnt vmcnt(4)" ::: "memory"); \
                      __builtin_amdgcn_sched_barrier(0); } while (0)

__global__ __launch_bounds__(512, 2) void gemm_bt8(const unsigned short* __restrict__ A,
                                                   const unsigned short* __restrict__ Bp,
                                                   float* __restrict__ C,
                                                   int M, int N, int K) {
  __shared__ __align__(16) char smem[131072];
  const int tid = threadIdx.x, lane = tid & 63, wv = tid >> 6;
  const int qi = lane & 15, g = lane >> 4;
  const int wm = wv >> 2, wn = wv & 3;

  // XCD-aware block swizzle (grid % 8 == 0)
  const int nwg = gridDim.x, cpx = nwg >> 3;
  const int id = blockIdx.x;
  const int swz = (id & 7) * cpx + (id >> 3);
  const int MT = M >> 8;
  const int m0 = (swz % MT) * 256, n0 = (swz / MT) * 256;
  const int NT = K >> 6;

  // staging: per half (128 rows x 64 cols), 2 passes of 64 rows; per pass each
  // wave writes 1KB (8 rows): row = pass*64 + wv*8 + (lane>>3), slot (lane&7).
  // source col pre-swizzled: ((lane&7)^(lane>>3))*8 elements.
  const int srowo = wv * 8 + (lane >> 3);
  const int scole = ((lane & 7) ^ (lane >> 3)) << 3;
  const size_t rA = (size_t)(m0 + srowo) * K + scole;
  const size_t rB = (size_t)(n0 + srowo) * K + scole;
  char* sdA = smem + wv * 1024;
  char* sdB = smem + 32768 + wv * 1024;

#define STG_A(D, H, KT) do { \
    GLDS16(A + rA + (size_t)((H)*128) * K + (size_t)(KT)*64,      sdA + (D)*65536 + (H)*16384); \
    GLDS16(A + rA + (size_t)((H)*128 + 64) * K + (size_t)(KT)*64, sdA + (D)*65536 + (H)*16384 + 8192); } while (0)
#define STG_B(D, H, KT) do { \
    GLDS16(Bp + rB + (size_t)((H)*128) * K + (size_t)(KT)*64,      sdB + (D)*65536 + (H)*16384); \
    GLDS16(Bp + rB + (size_t)((H)*128 + 64) * K + (size_t)(KT)*64, sdB + (D)*65536 + (H)*16384 + 8192); } while (0)

  // frag-read bases: row = (wm*128|wn*64) + f*16 + qi, byte = row*128 + ((kk*64+g*16)^sw)
  const int sw = (qi & 7) << 4;
  const char* frA = smem + (wm * 128 + qi) * 128;
  const char* frB = smem + 32768 + (wn * 64 + qi) * 128;

#define RDA4(D, F0) do { _Pragma("unroll") for (int f_ = 0; f_ < 4; ++f_) \
    _Pragma("unroll") for (int k_ = 0; k_ < 2; ++k_) \
      a[(F0) + f_][k_] = *(const s8v*)(frA + (D)*65536 + ((F0) + f_) * 2048 + (((k_ << 6) + (g << 4)) ^ sw)); } while (0)
#define RDB2(D, N0) do { _Pragma("unroll") for (int n_ = 0; n_ < 2; ++n_) \
    _Pragma("unroll") for (int k_ = 0; k_ < 2; ++k_) \
      b[(N0) + n_][k_] = *(const s8v*)(frB + (D)*65536 + ((N0) + n_) * 2048 + (((k_ << 6) + (g << 4)) ^ sw)); } while (0)
#define MQUAD(F0, N0) do { __builtin_amdgcn_s_setprio(1); \
    _Pragma("unroll") for (int f_ = 0; f_ < 4; ++f_) \
    _Pragma("unroll") for (int n_ = 0; n_ < 2; ++n_) \
    _Pragma("unroll") for (int k_ = 0; k_ < 2; ++k_) \
      mfma32(acc[(F0) + f_][(N0) + n_], a[(F0) + f_][k_], b[(N0) + n_][k_]); \
    __builtin_amdgcn_s_setprio(0); } while (0)

  f4v acc[8][4];
#pragma unroll
  for (int i = 0; i < 8; ++i)
#pragma unroll
    for (int j = 0; j < 4; ++j) acc[i][j] = (f4v)0.0f;

  // prologue: tile0 A+B into buf0, tile1 A into buf1 (6 halves, 12 loads/wave)
  STG_A(0, 0, 0); STG_A(0, 1, 0);
  STG_B(0, 0, 0); STG_B(0, 1, 0);
  STG_A(1, 0, 1); STG_A(1, 1, 1);
  WVM4;            // first 8 loads landed = tile 0 complete
  BAR;

  s8v a[8][2], b[4][2];
#pragma unroll 1
  for (int it = 0; it < NT / 2; ++it) {
    const int t = 2 * it;
    const int k2 = (t + 2 < NT) ? t + 2 : NT - 1;   // clamped: dest regions dead on tail
    const int k3 = (t + 3 < NT) ? t + 3 : NT - 1;
    // ---- phase 0: buf0 quad(0,0)
    RDA4(0, 0); RDB2(0, 0);
    STG_B(1, 0, t + 1);
    BAR; WLGKM; MQUAD(0, 0); BAR;
    // ---- phase 1: buf0 quad(1,0)
    RDA4(0, 4);
    STG_B(1, 1, t + 1);
    BAR; WLGKM; MQUAD(4, 0); BAR;
    // ---- phase 2: buf0 quad(0,1)
    RDB2(0, 2);
    STG_A(0, 0, k2);
    BAR; WLGKM; MQUAD(0, 2); BAR;
    // ---- phase 3: buf0 quad(1,1)
    STG_A(0, 1, k2);
    BAR; WLGKM; MQUAD(4, 2);
    WVM4;          // tile t+1 fully landed for all waves after this barrier
    BAR;
    // ---- phase 4: buf1 quad(0,0)
    RDA4(1, 0); RDB2(1, 0);
    STG_B(0, 0, k2);
    BAR; WLGKM; MQUAD(0, 0); BAR;
    // ---- phase 5: buf1 quad(1,0)
    RDA4(1, 4);
    STG_B(0, 1, k2);
    BAR; WLGKM; MQUAD(4, 0); BAR;
    // ---- phase 6: buf1 quad(0,1)
    RDB2(1, 2);
    STG_A(1, 0, k3);
    BAR; WLGKM; MQUAD(0, 2); BAR;
    // ---- phase 7: buf1 quad(1,1)
    STG_A(1, 1, k3);
    BAR; WLGKM; MQUAD(4, 2);
    WVM4;          // tile t+2 fully landed
    BAR;
  }

  asm volatile("s_waitcnt vmcnt(0)" ::: "memory");
  // MFMA->VALU read hazard guard (asm MFMAs bypass the hazard recognizer)
  asm volatile("s_nop 7\n\ts_nop 7" ::: "memory");
  const int r4 = g * 4;
#pragma unroll
  for (int fm = 0; fm < 8; ++fm)
#pragma unroll
    for (int fn = 0; fn < 4; ++fn)
#pragma unroll
      for (int r = 0; r < 4; ++r)
        C[(size_t)(m0 + wm * 128 + fm * 16 + r4 + r) * N + (n0 + wn * 64 + fn * 16 + qi)] =
            acc[fm][fn][r];
}

// ---------------------------------------------------------------------------
// RoPE + scatter (unchanged, proven)
// ---------------------------------------------------------------------------
__global__ __launch_bounds__(256) void rope_scatter(
    const float* __restrict__ qkv, const float* __restrict__ fr, const float* __restrict__ fi,
    unsigned short* __restrict__ qb, unsigned short* __restrict__ kb,
    unsigned short* __restrict__ vbuf, float* __restrict__ xk, float* __restrict__ xv) {
  const int idx = blockIdx.x * 256 + threadIdx.x;
  const int token = idx / 3072;
  const int col2  = (idx - token * 3072) * 2;
  const int pos   = token & 2047;
  f2v v = *(const f2v*)(qkv + (size_t)token * 6144 + col2);
  if (col2 < 4096) {
    const int j = (col2 & 127) >> 1;
    const float cr = fr[pos * 64 + j], ci = fi[pos * 64 + j];
    const float a = v[0] * cr - ci * v[1];
    const float o = v[0] * ci + v[1] * cr;
    *(unsigned*)(qb + (size_t)token * 4096 + col2) = (unsigned)f2b(a) | ((unsigned)f2b(o) << 16);
  } else if (col2 < 5120) {
    const int lc = col2 - 4096;
    const int j = (lc & 127) >> 1;
    const float cr = fr[pos * 64 + j], ci = fi[pos * 64 + j];
    const float a = v[0] * cr - ci * v[1];
    const float o = v[0] * ci + v[1] * cr;
    *(unsigned*)(kb + (size_t)token * 1024 + lc) = (unsigned)f2b(a) | ((unsigned)f2b(o) << 16);
    f2v w; w.x = a; w.y = o;
    *(f2v*)(xk + (size_t)token * 1024 + lc) = w;
  } else {
    const int lc = col2 - 5120;
    *(unsigned*)(vbuf + (size_t)token * 1024 + lc) = (unsigned)f2b(v[0]) | ((unsigned)f2b(v[1]) << 16);
    *(f2v*)(xv + (size_t)token * 1024 + lc) = v;
  }
}

// ---------------------------------------------------------------------------
// Causal GQA flash attention (unchanged from round 3, proven).
// ---------------------------------------------------------------------------
#define SCL_LOG2 0.12751744f   // (1/sqrt(128)) * log2(e)

__global__ __launch_bounds__(512, 4) void attn_fwd(
    const unsigned short* __restrict__ qb, const unsigned short* __restrict__ kb,
    const unsigned short* __restrict__ vb, unsigned short* __restrict__ ao) {
  __shared__ __align__(16) char smem[33792];   // K 16384 | V 16384; epilogue: f32-stage
  unsigned short* Ks = (unsigned short*)smem;
  char* Vt = smem + 16384;

  const int tid = threadIdx.x, lane = tid & 63, wv = tid >> 6;
  const int qi = lane & 15, g = lane >> 4;
  const int qtb = 15 - blockIdx.x;            // long blocks launch first
  const int h = blockIdx.y, b = blockIdx.z;
  const int kvh = h >> 2;
  const int q0 = qtb * 128;
  const int qrow = q0 + wv * 16 + qi;

  s8v qf[4];                                  // Q^T B-operand frags in regs
  {
    const unsigned short* qp = qb + (size_t)(b * 2048 + qrow) * 4096 + h * 128 + g * 8;
#pragma unroll
    for (int c = 0; c < 4; ++c) qf[c] = *(const s8v*)(qp + c * 32);
  }

  f4v oacc[8];
#pragma unroll
  for (int i = 0; i < 8; ++i) oacc[i] = (f4v)0.0f;
  float m_run = -3.0e38f, l_run = 0.0f;

  const int trow = tid >> 4;                  // 0..31
  const int tcol = (tid & 15) * 8;            // 0..120
  const unsigned short* kg = kb + (size_t)b * 2048 * 1024 + kvh * 128 + tcol;
  const unsigned short* vg = vb + (size_t)b * 2048 * 1024 + kvh * 128 + tcol;

  char* kw[2]; char* vw[2];
#pragma unroll
  for (int j = 0; j < 2; ++j) {
    const int row = trow + j * 32;            // key index within tile
    kw[j] = (char*)Ks + row * 256 + ((tcol * 2) ^ ((row & 7) << 4));
    const int kt = row >> 4, g4 = (row >> 2) & 3, kl = row & 3;
    const int dt = tcol >> 4, dl = tcol & 15;
    vw[j] = Vt + ((kt * 4 + g4) * 8 + dt) * 128 + kl * 32 + dl * 2;
  }

  const int ntiles = 2 * qtb + 2;
  const int my_qmax = q0 + wv * 16 + 15;      // wave-uniform causal gate

  s8v kreg0, kreg1, vreg0, vreg1;             // T14 prefetch registers
  kreg0 = *(const s8v*)(kg + (size_t)trow * 1024);
  kreg1 = *(const s8v*)(kg + (size_t)(trow + 32) * 1024);
  vreg0 = *(const s8v*)(vg + (size_t)trow * 1024);
  vreg1 = *(const s8v*)(vg + (size_t)(trow + 32) * 1024);

  for (int t = 0; t < ntiles; ++t) {
    __syncthreads();                          // consumers of tile t-1 done
    *(s8v*)kw[0] = kreg0; *(s8v*)kw[1] = kreg1;
    *(s8v*)vw[0] = vreg0; *(s8v*)vw[1] = vreg1;
    __syncthreads();
    if (t + 1 < ntiles) {                     // issue next tile's loads now
      const size_t base = (size_t)(t + 1) * 64 * 1024;
      kreg0 = *(const s8v*)(kg + base + (size_t)trow * 1024);
      kreg1 = *(const s8v*)(kg + base + (size_t)(trow + 32) * 1024);
      vreg0 = *(const s8v*)(vg + base + (size_t)trow * 1024);
      vreg1 = *(const s8v*)(vg + base + (size_t)(trow + 32) * 1024);
    }
    const int k0 = t * 64;
    if (k0 <= my_qmax) {                      // skip fully-masked tiles
      // ---- S^T[key][q] = K * Q^T
      f4v s4k[4];
#pragma unroll
      for (int kt = 0; kt < 4; ++kt) s4k[kt] = (f4v)0.0f;
      __builtin_amdgcn_s_setprio(1);
#pragma unroll
      for (int kt = 0; kt < 4; ++kt) {
        const char* kbase = (const char*)Ks + (kt * 16 + qi) * 256;
        const int sw = (qi & 7) << 4;
#pragma unroll
        for (int c = 0; c < 4; ++c) {
          s8v kf = *(const s8v*)(kbase + ((c * 64 + g * 16) ^ sw));
          mfma32(s4k[kt], kf, qf[c]);
        }
      }
      __builtin_amdgcn_s_setprio(0);
      asm volatile("s_nop 7\n\ts_nop 7"
        : "+v"(s4k[0]), "+v"(s4k[1]), "+v"(s4k[2]), "+v"(s4k[3]));

      // ---- mask + scale + online softmax (in place in s4k)
      float tm = -3.0e38f;
#pragma unroll
      for (int kt = 0; kt < 4; ++kt)
#pragma unroll
        for (int r = 0; r < 4; ++r) {
          const int keyg = k0 + kt * 16 + g * 4 + r;
          s4k[kt][r] = (keyg <= qrow) ? s4k[kt][r] * SCL_LOG2 : -3.0e38f;
          tm = fmaxf(tm, s4k[kt][r]);
        }
      tm = fmaxf(tm, __shfl_xor(tm, 16));
      tm = fmaxf(tm, __shfl_xor(tm, 32));
      const float m_new = fmaxf(m_run, tm);
      const float al = exp2f(m_run - m_new);
      float ps = 0.0f;
#pragma unroll
      for (int kt = 0; kt < 4; ++kt)
#pragma unroll
        for (int r = 0; r < 4; ++r) {
          s4k[kt][r] = exp2f(s4k[kt][r] - m_new);
          ps += s4k[kt][r];
        }
      ps += __shfl_xor(ps, 16);
      ps += __shfl_xor(ps, 32);
      l_run = l_run * al + ps;
      m_run = m_new;
#pragma unroll
      for (int i = 0; i < 8; ++i) oacc[i] *= al;

      s4v pf[4];
#pragma unroll
      for (int kt = 0; kt < 4; ++kt)
#pragma unroll
        for (int r = 0; r < 4; ++r) pf[kt][r] = (short)f2b(s4k[kt][r]);

      // ---- O^T += V^T * P^T   (A-frags via hardware transpose read)
#pragma unroll
      for (int kt = 0; kt < 4; ++kt) {
        const char* tb = Vt + (kt * 4 + g) * 1024 + qi * 8;
        s4v vf[8];
#pragma unroll
        for (int dt = 0; dt < 8; ++dt) vf[dt] = tr_read(tb, dt * 128);
        asm volatile("s_waitcnt lgkmcnt(0)" ::: "memory");
        __builtin_amdgcn_sched_barrier(0);
        __builtin_amdgcn_s_setprio(1);
#pragma unroll
        for (int dt = 0; dt < 8; ++dt) mfma16(oacc[dt], vf[dt], pf[kt]);
        __builtin_amdgcn_s_setprio(0);
      }
    }
  }

  // ---- epilogue: O^T -> LDS (two half-passes) -> coalesced 32B bf16 stores
  __syncthreads();
  asm volatile("s_nop 7\n\ts_nop 7"
    : "+v"(oacc[0]), "+v"(oacc[1]), "+v"(oacc[2]), "+v"(oacc[3]),
      "+v"(oacc[4]), "+v"(oacc[5]), "+v"(oacc[6]), "+v"(oacc[7]));
  const float inv = 1.0f / l_run;
  float* Ost = (float*)smem;                  // [4 waves][16 q][132 f32] per pass
  const int eq = tid >> 3, ed0 = (tid & 7) * 16;
  const int elw = eq >> 4, eql = eq & 15;
#pragma unroll
  for (int half = 0; half < 2; ++half) {
    if ((wv >> 2) == half) {
      const int lw = wv & 3;
#pragma unroll
      for (int dt = 0; dt < 8; ++dt)
#pragma unroll
        for (int r = 0; r < 4; ++r)
          Ost[lw * 2112 + qi * 132 + dt * 16 + g * 4 + r] = oacc[dt][r] * inv;
    }
    __syncthreads();
    const float* src = Ost + elw * 2112 + eql * 132 + ed0;
    f4v a0 = *(const f4v*)(src), a1 = *(const f4v*)(src + 4),
        a2 = *(const f4v*)(src + 8), a3 = *(const f4v*)(src + 12);
    u4v r0, r1;
    r0.x = pk2(a0[0], a0[1]); r0.y = pk2(a0[2], a0[3]);
    r0.z = pk2(a1[0], a1[1]); r0.w = pk2(a1[2], a1[3]);
    r1.x = pk2(a2[0], a2[1]); r1.y = pk2(a2[2], a2[3]);
    r1.z = pk2(a3[0], a3[1]); r1.w = pk2(a3[2], a3[3]);
    unsigned short* dst = ao + (size_t)(b * 2048 + q0 + half * 64 + eq) * 4096 + h * 128 + ed0;
    *(u4v*)dst = r0;
    *(u4v*)(dst + 8) = r1;
    __syncthreads();
  }
}

// ---------------------------------------------------------------------------
// Host launcher. Workspace layout (needs ws_size >= 268,435,456 B).
// ---------------------------------------------------------------------------
extern "C" void kernel_launch(void* const* d_in, const int* in_sizes, int n_in,
                              void* d_out, int out_size, void* d_ws, size_t ws_size,
                              hipStream_t stream) {
  (void)in_sizes; (void)n_in; (void)out_size; (void)ws_size;
  const float* x  = (const float*)d_in[0];
  const float* wq = (const float*)d_in[1];
  const float* wk = (const float*)d_in[2];
  const float* wv = (const float*)d_in[3];
  const float* wo = (const float*)d_in[4];
  const float* fr = (const float*)d_in[5];
  const float* fi = (const float*)d_in[6];

  float* out = (float*)d_out;
  float* xk  = out + 16777216;
  float* xv  = xk + 4194304;

  char* ws = (char*)d_ws;
  unsigned short* xb    = (unsigned short*)(ws);
  unsigned short* wqkvb = (unsigned short*)(ws + 33554432);
  unsigned short* wob   = (unsigned short*)(ws + 83886080);
  float*          qkv   = (float*)(ws + 117440512);
  unsigned short* aob   = (unsigned short*)(ws + 117440512);  // reuse after rope
  unsigned short* qbuf  = (unsigned short*)(ws + 218103808);
  unsigned short* kbuf  = (unsigned short*)(ws + 251658240);
  unsigned short* vbuf  = (unsigned short*)(ws + 260046848);

  cvt_bf16<<<16384, 256, 0, stream>>>(x,  xb, 4194304);
  cvt_bf16<<<16384, 256, 0, stream>>>(wq, wqkvb, 4194304);
  cvt_bf16<<<4096,  256, 0, stream>>>(wk, wqkvb + 16777216, 1048576);
  cvt_bf16<<<4096,  256, 0, stream>>>(wv, wqkvb + 20971520, 1048576);
  cvt_bf16<<<16384, 256, 0, stream>>>(wo, wob, 4194304);

  gemm_bt8<<<384, 512, 0, stream>>>(xb, wqkvb, qkv, 4096, 6144, 4096);
  rope_scatter<<<49152, 256, 0, stream>>>(qkv, fr, fi, qbuf, kbuf, vbuf, xk, xv);
  attn_fwd<<<dim3(16, 32, 2), 512, 0, stream>>>(qbuf, kbuf, vbuf, aob);
  gemm_bt8<<<256, 512, 0, stream>>>(aob, wob, out, 4096, 4096, 4096);
}

// Round 5
// 693.423 us; speedup vs baseline: 1.0966x; 1.0966x over previous
//
#include <hip/hip_runtime.h>
#include <hip/hip_bf16.h>

// ---------------------------------------------------------------------------
// Attention block: B=2 S=2048 D=4096 H=32 KV=8 HD=128 (GQA N_REP=4, causal)
// Pipeline: cvt -> GEMM8-splitK(qkv, bf16 partials) -> RoPE/sum/scatter
//           -> flash-attn -> GEMM8(out)
// ---------------------------------------------------------------------------

typedef __attribute__((ext_vector_type(8))) short  s8v;   // 8 x bf16 (4 VGPR)
typedef __attribute__((ext_vector_type(4))) short  s4v;   // 4 x bf16 (2 VGPR)
typedef __attribute__((ext_vector_type(4))) float  f4v;
typedef __attribute__((ext_vector_type(2))) float  f2v;
typedef __attribute__((ext_vector_type(2))) unsigned int u2v;
typedef __attribute__((ext_vector_type(4))) unsigned int u4v;

typedef __attribute__((address_space(3))) void lds_void;
typedef __attribute__((address_space(1))) void g_void;

#define GLDS16(gp, lp) __builtin_amdgcn_global_load_lds((g_void*)(gp), (lds_void*)(lp), 16, 0, 0)

__device__ __forceinline__ unsigned short f2b(float f) {  // f32 -> bf16 RNE
  unsigned u = __builtin_bit_cast(unsigned, f);
  u += 0x7fffu + ((u >> 16) & 1u);
  return (unsigned short)(u >> 16);
}
__device__ __forceinline__ unsigned pk2(float a, float b) {
  return (unsigned)f2b(a) | ((unsigned)f2b(b) << 16);
}
__device__ __forceinline__ float b2f(unsigned short h) {
  return __builtin_bit_cast(float, (unsigned)h << 16);
}

// inline-asm MFMAs (volatile; s_nop guards at every MFMA->VALU read-back)
__device__ __forceinline__ void mfma32(f4v& d, s8v a, s8v b) {
  asm volatile("v_mfma_f32_16x16x32_bf16 %0, %1, %2, %0" : "+v"(d) : "v"(a), "v"(b));
}
__device__ __forceinline__ void mfma16(f4v& d, s4v a, s4v b) {
  asm volatile("v_mfma_f32_16x16x16_bf16 %0, %1, %2, %0" : "+v"(d) : "v"(a), "v"(b));
}
__device__ __forceinline__ s4v tr_read(const char* p, int imm) {
  s4v r;
  asm volatile("ds_read_b64_tr_b16 %0, %1 offset:%2"
               : "=v"(r) : "v"((lds_void*)p), "n"(imm));
  return r;
}

// ---------------------------------------------------------------------------
// f32 -> bf16 convert
// ---------------------------------------------------------------------------
__global__ __launch_bounds__(256) void cvt_bf16(const float* __restrict__ s,
                                                unsigned short* __restrict__ d, int n4) {
  const int i = blockIdx.x * 256 + threadIdx.x;
  if (i >= n4) return;
  f4v v = *(const f4v*)(s + (size_t)i * 4);
  u2v r;
  r.x = pk2(v[0], v[1]);
  r.y = pk2(v[2], v[3]);
  *(u2v*)(d + (size_t)i * 4) = r;
}

// ---------------------------------------------------------------------------
// 8-phase GEMM, C = A[M][Ks] * B[N][Ks]^T over K range [kOff, kOff+Klen).
// 256x256 tile, BK=64, 512 thr = 8 waves (2M x 4N), 128 KiB LDS double-buffer.
// grid = nTiles (OUTB=0, f32 C) or 2*nTiles (OUTB=1: splitK halves -> bf16
// partial C at Cout + half*M*N). 3 exact dispatch rounds for qkv (768/256).
// Swizzle: byte-in-row ^= (row&7)<<4 via pre-swizzled global source column.
// Race-free stage plan (verified r4): per iter tiles t,t+1; slots ph0..7 =
// t+1.B0, t+1.B1, t+2.A0, t+2.A1, t+2.B0, t+2.B1, t+3.A0, t+3.A1;
// vmcnt(4) gates at ph3/ph7 before the closing barrier.
// ---------------------------------------------------------------------------
#define BAR      asm volatile("s_barrier" ::: "memory")
#define WLGKM    do { asm volatile("s_waitcnt lgkmcnt(0)" ::: "memory"); \
                      __builtin_amdgcn_sched_barrier(0); } while (0)
#define WVM4     do { asm volatile("s_waitcnt vmcnt(4)" ::: "memory"); \
                      __builtin_amdgcn_sched_barrier(0); } while (0)

template <int OUTB>
__global__ __launch_bounds__(512, 2) void gemm_bt8(const unsigned short* __restrict__ A,
                                                   const unsigned short* __restrict__ Bp,
                                                   void* __restrict__ Cout,
                                                   int M, int N, int Ks, int Klen,
                                                   int nTiles) {
  __shared__ __align__(16) char smem[131072];
  const int tid = threadIdx.x, lane = tid & 63, wv = tid >> 6;
  const int qi = lane & 15, g = lane >> 4;
  const int wm = wv >> 2, wn = wv & 3;

  // XCD-aware block swizzle (grid % 8 == 0)
  const int nwg = gridDim.x, cpx = nwg >> 3;
  const int id = blockIdx.x;
  const int swz = (id & 7) * cpx + (id >> 3);
  const int half = swz / nTiles;            // 0 unless splitK grid
  const int tile = swz - half * nTiles;
  const int kOff = half * Klen;
  const int MT = M >> 8;
  const int m0 = (tile % MT) * 256, n0 = (tile / MT) * 256;
  const int NT = Klen >> 6;

  const int srowo = wv * 8 + (lane >> 3);
  const int scole = ((lane & 7) ^ (lane >> 3)) << 3;
  const size_t rA = (size_t)(m0 + srowo) * Ks + kOff + scole;
  const size_t rB = (size_t)(n0 + srowo) * Ks + kOff + scole;
  char* sdA = smem + wv * 1024;
  char* sdB = smem + 32768 + wv * 1024;

#define STG_A(D, H, KT) do { \
    GLDS16(A + rA + (size_t)((H)*128) * Ks + (size_t)(KT)*64,      sdA + (D)*65536 + (H)*16384); \
    GLDS16(A + rA + (size_t)((H)*128 + 64) * Ks + (size_t)(KT)*64, sdA + (D)*65536 + (H)*16384 + 8192); } while (0)
#define STG_B(D, H, KT) do { \
    GLDS16(Bp + rB + (size_t)((H)*128) * Ks + (size_t)(KT)*64,      sdB + (D)*65536 + (H)*16384); \
    GLDS16(Bp + rB + (size_t)((H)*128 + 64) * Ks + (size_t)(KT)*64, sdB + (D)*65536 + (H)*16384 + 8192); } while (0)

  const int sw = (qi & 7) << 4;
  const char* frA = smem + (wm * 128 + qi) * 128;
  const char* frB = smem + 32768 + (wn * 64 + qi) * 128;

#define RDA4(D, F0) do { _Pragma("unroll") for (int f_ = 0; f_ < 4; ++f_) \
    _Pragma("unroll") for (int k_ = 0; k_ < 2; ++k_) \
      a[(F0) + f_][k_] = *(const s8v*)(frA + (D)*65536 + ((F0) + f_) * 2048 + (((k_ << 6) + (g << 4)) ^ sw)); } while (0)
#define RDB2(D, N0) do { _Pragma("unroll") for (int n_ = 0; n_ < 2; ++n_) \
    _Pragma("unroll") for (int k_ = 0; k_ < 2; ++k_) \
      b[(N0) + n_][k_] = *(const s8v*)(frB + (D)*65536 + ((N0) + n_) * 2048 + (((k_ << 6) + (g << 4)) ^ sw)); } while (0)
#define MQUAD(F0, N0) do { __builtin_amdgcn_s_setprio(1); \
    _Pragma("unroll") for (int f_ = 0; f_ < 4; ++f_) \
    _Pragma("unroll") for (int n_ = 0; n_ < 2; ++n_) \
    _Pragma("unroll") for (int k_ = 0; k_ < 2; ++k_) \
      mfma32(acc[(F0) + f_][(N0) + n_], a[(F0) + f_][k_], b[(N0) + n_][k_]); \
    __builtin_amdgcn_s_setprio(0); } while (0)

  f4v acc[8][4];
#pragma unroll
  for (int i = 0; i < 8; ++i)
#pragma unroll
    for (int j = 0; j < 4; ++j) acc[i][j] = (f4v)0.0f;

  // prologue: tile0 A+B into buf0, tile1 A into buf1
  STG_A(0, 0, 0); STG_A(0, 1, 0);
  STG_B(0, 0, 0); STG_B(0, 1, 0);
  STG_A(1, 0, 1); STG_A(1, 1, 1);
  WVM4;
  BAR;

  s8v a[8][2], b[4][2];
#pragma unroll 1
  for (int it = 0; it < NT / 2; ++it) {
    const int t = 2 * it;
    const int k2 = (t + 2 < NT) ? t + 2 : NT - 1;   // clamped: dest dead on tail
    const int k3 = (t + 3 < NT) ? t + 3 : NT - 1;
    RDA4(0, 0); RDB2(0, 0);
    STG_B(1, 0, t + 1);
    BAR; WLGKM; MQUAD(0, 0); BAR;
    RDA4(0, 4);
    STG_B(1, 1, t + 1);
    BAR; WLGKM; MQUAD(4, 0); BAR;
    RDB2(0, 2);
    STG_A(0, 0, k2);
    BAR; WLGKM; MQUAD(0, 2); BAR;
    STG_A(0, 1, k2);
    BAR; WLGKM; MQUAD(4, 2);
    WVM4;
    BAR;
    RDA4(1, 0); RDB2(1, 0);
    STG_B(0, 0, k2);
    BAR; WLGKM; MQUAD(0, 0); BAR;
    RDA4(1, 4);
    STG_B(0, 1, k2);
    BAR; WLGKM; MQUAD(4, 0); BAR;
    RDB2(1, 2);
    STG_A(1, 0, k3);
    BAR; WLGKM; MQUAD(0, 2); BAR;
    STG_A(1, 1, k3);
    BAR; WLGKM; MQUAD(4, 2);
    WVM4;
    BAR;
  }

  asm volatile("s_waitcnt vmcnt(0)" ::: "memory");
  asm volatile("s_nop 7\n\ts_nop 7" ::: "memory");   // MFMA->VALU hazard guard
  const int r4 = g * 4;
  if (OUTB) {
    unsigned short* Cb = (unsigned short*)Cout + (size_t)half * M * N;
#pragma unroll
    for (int fm = 0; fm < 8; ++fm)
#pragma unroll
      for (int fn = 0; fn < 4; ++fn)
#pragma unroll
        for (int r = 0; r < 4; ++r)
          Cb[(size_t)(m0 + wm * 128 + fm * 16 + r4 + r) * N + (n0 + wn * 64 + fn * 16 + qi)] =
              f2b(acc[fm][fn][r]);
  } else {
    float* Cf = (float*)Cout;
#pragma unroll
    for (int fm = 0; fm < 8; ++fm)
#pragma unroll
      for (int fn = 0; fn < 4; ++fn)
#pragma unroll
        for (int r = 0; r < 4; ++r)
          Cf[(size_t)(m0 + wm * 128 + fm * 16 + r4 + r) * N + (n0 + wn * 64 + fn * 16 + qi)] =
              acc[fm][fn][r];
  }
}

// ---------------------------------------------------------------------------
// RoPE + splitK-sum + scatter. qkv partials: two bf16 [4096][6144] halves.
// ---------------------------------------------------------------------------
__global__ __launch_bounds__(256) void rope_scatter(
    const unsigned short* __restrict__ qkvp, const float* __restrict__ fr,
    const float* __restrict__ fi,
    unsigned short* __restrict__ qb, unsigned short* __restrict__ kb,
    unsigned short* __restrict__ vbuf, float* __restrict__ xk, float* __restrict__ xv) {
  const int idx = blockIdx.x * 256 + threadIdx.x;
  const int token = idx / 3072;
  const int col2  = (idx - token * 3072) * 2;
  const int pos   = token & 2047;
  const unsigned u1 = *(const unsigned*)(qkvp + (size_t)token * 6144 + col2);
  const unsigned u2 = *(const unsigned*)(qkvp + 25165824u + (size_t)token * 6144 + col2);
  float v0 = b2f((unsigned short)u1) + b2f((unsigned short)u2);
  float v1 = b2f((unsigned short)(u1 >> 16)) + b2f((unsigned short)(u2 >> 16));
  if (col2 < 4096) {
    const int j = (col2 & 127) >> 1;
    const float cr = fr[pos * 64 + j], ci = fi[pos * 64 + j];
    const float a = v0 * cr - ci * v1;
    const float o = v0 * ci + v1 * cr;
    *(unsigned*)(qb + (size_t)token * 4096 + col2) = pk2(a, o);
  } else if (col2 < 5120) {
    const int lc = col2 - 4096;
    const int j = (lc & 127) >> 1;
    const float cr = fr[pos * 64 + j], ci = fi[pos * 64 + j];
    const float a = v0 * cr - ci * v1;
    const float o = v0 * ci + v1 * cr;
    *(unsigned*)(kb + (size_t)token * 1024 + lc) = pk2(a, o);
    f2v w; w.x = a; w.y = o;
    *(f2v*)(xk + (size_t)token * 1024 + lc) = w;
  } else {
    const int lc = col2 - 5120;
    *(unsigned*)(vbuf + (size_t)token * 1024 + lc) = pk2(v0, v1);
    f2v w; w.x = v0; w.y = v1;
    *(f2v*)(xv + (size_t)token * 1024 + lc) = w;
  }
}

// ---------------------------------------------------------------------------
// Causal GQA flash attention (round-3 structure + unmasked fast path + T13
// defer-max). 512 thr = 8 waves x 16 q-rows, 64-key tiles.
// ---------------------------------------------------------------------------
#define SCL_LOG2 0.12751744f   // (1/sqrt(128)) * log2(e)

__global__ __launch_bounds__(512, 4) void attn_fwd(
    const unsigned short* __restrict__ qb, const unsigned short* __restrict__ kb,
    const unsigned short* __restrict__ vb, unsigned short* __restrict__ ao) {
  __shared__ __align__(16) char smem[33792];   // K 16384 | V 16384; epilogue stage
  unsigned short* Ks = (unsigned short*)smem;
  char* Vt = smem + 16384;

  const int tid = threadIdx.x, lane = tid & 63, wv = tid >> 6;
  const int qi = lane & 15, g = lane >> 4;
  const int qtb = 15 - blockIdx.x;            // long blocks launch first
  const int h = blockIdx.y, b = blockIdx.z;
  const int kvh = h >> 2;
  const int q0 = qtb * 128;
  const int qrow = q0 + wv * 16 + qi;

  s8v qf[4];
  {
    const unsigned short* qp = qb + (size_t)(b * 2048 + qrow) * 4096 + h * 128 + g * 8;
#pragma unroll
    for (int c = 0; c < 4; ++c) qf[c] = *(const s8v*)(qp + c * 32);
  }

  f4v oacc[8];
#pragma unroll
  for (int i = 0; i < 8; ++i) oacc[i] = (f4v)0.0f;
  float m_run = -3.0e38f, l_run = 0.0f;

  const int trow = tid >> 4;
  const int tcol = (tid & 15) * 8;
  const unsigned short* kg = kb + (size_t)b * 2048 * 1024 + kvh * 128 + tcol;
  const unsigned short* vg = vb + (size_t)b * 2048 * 1024 + kvh * 128 + tcol;

  char* kw[2]; char* vw[2];
#pragma unroll
  for (int j = 0; j < 2; ++j) {
    const int row = trow + j * 32;
    kw[j] = (char*)Ks + row * 256 + ((tcol * 2) ^ ((row & 7) << 4));
    const int kt = row >> 4, g4 = (row >> 2) & 3, kl = row & 3;
    const int dt = tcol >> 4, dl = tcol & 15;
    vw[j] = Vt + ((kt * 4 + g4) * 8 + dt) * 128 + kl * 32 + dl * 2;
  }

  const int ntiles = 2 * qtb + 2;
  const int my_qmax = q0 + wv * 16 + 15;
  const int wq_lo = q0 + wv * 16;             // min q-row in wave

  s8v kreg0, kreg1, vreg0, vreg1;
  kreg0 = *(const s8v*)(kg + (size_t)trow * 1024);
  kreg1 = *(const s8v*)(kg + (size_t)(trow + 32) * 1024);
  vreg0 = *(const s8v*)(vg + (size_t)trow * 1024);
  vreg1 = *(const s8v*)(vg + (size_t)(trow + 32) * 1024);

  for (int t = 0; t < ntiles; ++t) {
    __syncthreads();
    *(s8v*)kw[0] = kreg0; *(s8v*)kw[1] = kreg1;
    *(s8v*)vw[0] = vreg0; *(s8v*)vw[1] = vreg1;
    __syncthreads();
    if (t + 1 < ntiles) {
      const size_t base = (size_t)(t + 1) * 64 * 1024;
      kreg0 = *(const s8v*)(kg + base + (size_t)trow * 1024);
      kreg1 = *(const s8v*)(kg + base + (size_t)(trow + 32) * 1024);
      vreg0 = *(const s8v*)(vg + base + (size_t)trow * 1024);
      vreg1 = *(const s8v*)(vg + base + (size_t)(trow + 32) * 1024);
    }
    const int k0 = t * 64;
    if (k0 <= my_qmax) {
      // ---- S^T[key][q] = K * Q^T
      f4v s4k[4];
#pragma unroll
      for (int kt = 0; kt < 4; ++kt) s4k[kt] = (f4v)0.0f;
      __builtin_amdgcn_s_setprio(1);
#pragma unroll
      for (int kt = 0; kt < 4; ++kt) {
        const char* kbase = (const char*)Ks + (kt * 16 + qi) * 256;
        const int sw = (qi & 7) << 4;
#pragma unroll
        for (int c = 0; c < 4; ++c) {
          s8v kf = *(const s8v*)(kbase + ((c * 64 + g * 16) ^ sw));
          mfma32(s4k[kt], kf, qf[c]);
        }
      }
      __builtin_amdgcn_s_setprio(0);
      asm volatile("s_nop 7\n\ts_nop 7"
        : "+v"(s4k[0]), "+v"(s4k[1]), "+v"(s4k[2]), "+v"(s4k[3]));

      // ---- scale (+mask only on partial tiles); per-lane running max
      float tm = -3.0e38f;
      if (k0 + 64 <= wq_lo) {                 // wave-uniform: fully unmasked
#pragma unroll
        for (int kt = 0; kt < 4; ++kt)
#pragma unroll
          for (int r = 0; r < 4; ++r) {
            s4k[kt][r] *= SCL_LOG2;
            tm = fmaxf(tm, s4k[kt][r]);
          }
      } else {                                // diagonal/partial tile
#pragma unroll
        for (int kt = 0; kt < 4; ++kt)
#pragma unroll
          for (int r = 0; r < 4; ++r) {
            const int keyg = k0 + kt * 16 + g * 4 + r;
            s4k[kt][r] = (keyg <= qrow) ? s4k[kt][r] * SCL_LOG2 : -3.0e38f;
            tm = fmaxf(tm, s4k[kt][r]);
          }
      }
      tm = fmaxf(tm, __shfl_xor(tm, 16));
      tm = fmaxf(tm, __shfl_xor(tm, 32));

      // ---- T13 defer-max: skip rescale when max growth <= 8 (P <= 256)
      if (!__all(tm - m_run <= 8.0f)) {
        const float m_new = fmaxf(m_run, tm);
        const float al = exp2f(m_run - m_new);
#pragma unroll
        for (int i = 0; i < 8; ++i) oacc[i] *= al;
        l_run *= al;
        m_run = m_new;
      }
      float ps = 0.0f;
#pragma unroll
      for (int kt = 0; kt < 4; ++kt)
#pragma unroll
        for (int r = 0; r < 4; ++r) {
          s4k[kt][r] = exp2f(s4k[kt][r] - m_run);
          ps += s4k[kt][r];
        }
      ps += __shfl_xor(ps, 16);
      ps += __shfl_xor(ps, 32);
      l_run += ps;

      s4v pf[4];
#pragma unroll
      for (int kt = 0; kt < 4; ++kt)
#pragma unroll
        for (int r = 0; r < 4; ++r) pf[kt][r] = (short)f2b(s4k[kt][r]);

      // ---- O^T += V^T * P^T   (A-frags via hardware transpose read)
#pragma unroll
      for (int kt = 0; kt < 4; ++kt) {
        const char* tb = Vt + (kt * 4 + g) * 1024 + qi * 8;
        s4v vf[8];
#pragma unroll
        for (int dt = 0; dt < 8; ++dt) vf[dt] = tr_read(tb, dt * 128);
        asm volatile("s_waitcnt lgkmcnt(0)" ::: "memory");
        __builtin_amdgcn_sched_barrier(0);
        __builtin_amdgcn_s_setprio(1);
#pragma unroll
        for (int dt = 0; dt < 8; ++dt) mfma16(oacc[dt], vf[dt], pf[kt]);
        __builtin_amdgcn_s_setprio(0);
      }
    }
  }

  // ---- epilogue: O^T -> LDS (two half-passes) -> coalesced 32B bf16 stores
  __syncthreads();
  asm volatile("s_nop 7\n\ts_nop 7"
    : "+v"(oacc[0]), "+v"(oacc[1]), "+v"(oacc[2]), "+v"(oacc[3]),
      "+v"(oacc[4]), "+v"(oacc[5]), "+v"(oacc[6]), "+v"(oacc[7]));
  const float inv = 1.0f / l_run;
  float* Ost = (float*)smem;
  const int eq = tid >> 3, ed0 = (tid & 7) * 16;
  const int elw = eq >> 4, eql = eq & 15;
#pragma unroll
  for (int half = 0; half < 2; ++half) {
    if ((wv >> 2) == half) {
      const int lw = wv & 3;
#pragma unroll
      for (int dt = 0; dt < 8; ++dt)
#pragma unroll
        for (int r = 0; r < 4; ++r)
          Ost[lw * 2112 + qi * 132 + dt * 16 + g * 4 + r] = oacc[dt][r] * inv;
    }
    __syncthreads();
    const float* src = Ost + elw * 2112 + eql * 132 + ed0;
    f4v a0 = *(const f4v*)(src), a1 = *(const f4v*)(src + 4),
        a2 = *(const f4v*)(src + 8), a3 = *(const f4v*)(src + 12);
    u4v r0, r1;
    r0.x = pk2(a0[0], a0[1]); r0.y = pk2(a0[2], a0[3]);
    r0.z = pk2(a1[0], a1[1]); r0.w = pk2(a1[2], a1[3]);
    r1.x = pk2(a2[0], a2[1]); r1.y = pk2(a2[2], a2[3]);
    r1.z = pk2(a3[0], a3[1]); r1.w = pk2(a3[2], a3[3]);
    unsigned short* dst = ao + (size_t)(b * 2048 + q0 + half * 64 + eq) * 4096 + h * 128 + ed0;
    *(u4v*)dst = r0;
    *(u4v*)(dst + 8) = r1;
    __syncthreads();
  }
}

// ---------------------------------------------------------------------------
// Host launcher. Workspace layout (needs ws_size >= 268,435,456 B):
//   [0,32M)     xb bf16        [32M,80M)   wqkv bf16
//   [80M,112M)  wo bf16        [112M,208M) qkv bf16 partials C1|C2 (2x48M)
//                              (reused as attn_out bf16 after rope)
//   [208M,240M) q bf16         [240M,248M) k bf16    [248M,256M) v bf16
// ---------------------------------------------------------------------------
extern "C" void kernel_launch(void* const* d_in, const int* in_sizes, int n_in,
                              void* d_out, int out_size, void* d_ws, size_t ws_size,
                              hipStream_t stream) {
  (void)in_sizes; (void)n_in; (void)out_size; (void)ws_size;
  const float* x  = (const float*)d_in[0];
  const float* wq = (const float*)d_in[1];
  const float* wk = (const float*)d_in[2];
  const float* wv = (const float*)d_in[3];
  const float* wo = (const float*)d_in[4];
  const float* fr = (const float*)d_in[5];
  const float* fi = (const float*)d_in[6];

  float* out = (float*)d_out;
  float* xk  = out + 16777216;
  float* xv  = xk + 4194304;

  char* ws = (char*)d_ws;
  unsigned short* xb    = (unsigned short*)(ws);
  unsigned short* wqkvb = (unsigned short*)(ws + 33554432);
  unsigned short* wob   = (unsigned short*)(ws + 83886080);
  unsigned short* qkvb  = (unsigned short*)(ws + 117440512);  // C1|C2 bf16
  unsigned short* aob   = (unsigned short*)(ws + 117440512);  // reuse after rope
  unsigned short* qbuf  = (unsigned short*)(ws + 218103808);
  unsigned short* kbuf  = (unsigned short*)(ws + 251658240);
  unsigned short* vbuf  = (unsigned short*)(ws + 260046848);

  cvt_bf16<<<16384, 256, 0, stream>>>(x,  xb, 4194304);
  cvt_bf16<<<16384, 256, 0, stream>>>(wq, wqkvb, 4194304);
  cvt_bf16<<<4096,  256, 0, stream>>>(wk, wqkvb + 16777216, 1048576);
  cvt_bf16<<<4096,  256, 0, stream>>>(wv, wqkvb + 20971520, 1048576);
  cvt_bf16<<<16384, 256, 0, stream>>>(wo, wob, 4194304);

  // qkv: splitK (K halves of 2048), 768 blocks = 3 exact rounds on 256 CUs
  gemm_bt8<1><<<768, 512, 0, stream>>>(xb, wqkvb, qkvb, 4096, 6144, 4096, 2048, 384);
  rope_scatter<<<49152, 256, 0, stream>>>(qkvb, fr, fi, qbuf, kbuf, vbuf, xk, xv);
  attn_fwd<<<dim3(16, 32, 2), 512, 0, stream>>>(qbuf, kbuf, vbuf, aob);
  gemm_bt8<0><<<256, 512, 0, stream>>>(aob, wob, out, 4096, 4096, 4096, 4096, 256);
}